// Round 10
// baseline (10736.578 us; speedup 1.0000x reference)
//
#include <hip/hip_runtime.h>
#include <hip/hip_bf16.h>
#include <cstdint>

// MoRALinear: out[m,o] = sum_i x[m,i] * (W[o,i] + A[o&1023, i&1023]) + b[o]
// R10: 256x256 tile, BK=32, 8-wave, mfma_32x32x16, fragment-major panels,
//      2-SLOT LDS ring (64 KB) -> 2 blocks/CU co-resident. Cross-block TLP
//      provides the LDS-read / MFMA overlap that intra-block schedules
//      (R5-R9) could not: co-resident blocks are not barrier-synced, so one
//      block's MFMA epoch covers the other's read epoch (m114 mechanism).
//      setprio(1) around MFMA (T5 prereq now present: cross-block role split).

typedef __attribute__((ext_vector_type(8))) short bf16x8;
typedef __attribute__((ext_vector_type(16))) float f32x16;
typedef __attribute__((ext_vector_type(4))) float fvec4;

static constexpr int MTOT = 16384;   // B*S
static constexpr int KF   = 4096;    // IN_F
static constexpr int NF   = 4096;    // OUT_F
static constexpr int BM = 256, BN = 256, BK = 32;
static constexpr int TILE = BM * BK;          // 8192 bf16 elems per K-tile panel
static constexpr int KT = KF / BK;            // 128 K-tiles
static constexpr int MB = MTOT / BM;          // 64
static constexpr int NB = NF / BN;            // 16

// ---------------- prep: x -> bf16, fragment-major (32x32x16 frags) -----------
__global__ __launch_bounds__(256) void tile_x_kernel(const float* __restrict__ x,
                                                     __hip_bfloat16* __restrict__ xt) {
    int blk = blockIdx.x;               // mb*KT + kt ; grid = 64*128
    int mb = blk >> 7, kt = blk & 127;
    int tid = threadIdx.x;
    __hip_bfloat16* dst = xt + (size_t)blk * TILE;
#pragma unroll
    for (int it = 0; it < 4; ++it) {
        int e = (it * 256 + tid) * 8;   // element within tile, 0..8191
        int f = e >> 9;                 // fragment 0..15
        int l = (e >> 3) & 63;          // lane 0..63
        int rb = f >> 1, kh = f & 1;
        int row = mb * BM + rb * 32 + (l & 31);
        int k0  = kt * BK + kh * 16 + (l >> 5) * 8;
        const fvec4* s = (const fvec4*)(x + (size_t)row * KF + k0);
        fvec4 v0 = s[0], v1 = s[1];
        union { bf16x8 v; __hip_bfloat16 h[8]; } o;
        o.h[0] = __float2bfloat16(v0[0]); o.h[1] = __float2bfloat16(v0[1]);
        o.h[2] = __float2bfloat16(v0[2]); o.h[3] = __float2bfloat16(v0[3]);
        o.h[4] = __float2bfloat16(v1[0]); o.h[5] = __float2bfloat16(v1[1]);
        o.h[6] = __float2bfloat16(v1[2]); o.h[7] = __float2bfloat16(v1[3]);
        *(bf16x8*)(dst + e) = o.v;
    }
}

// ---------------- prep: W' = W + tiled(A) -> bf16 fragment-major -------------
__global__ __launch_bounds__(256) void tile_w_kernel(const float* __restrict__ W,
                                                     const float* __restrict__ A,
                                                     __hip_bfloat16* __restrict__ wt) {
    int blk = blockIdx.x;               // nb*KT + kt ; grid = 16*128
    int nb = blk >> 7, kt = blk & 127;
    int tid = threadIdx.x;
    __hip_bfloat16* dst = wt + (size_t)blk * TILE;
#pragma unroll
    for (int it = 0; it < 4; ++it) {
        int e = (it * 256 + tid) * 8;
        int f = e >> 9;
        int l = (e >> 3) & 63;
        int rb = f >> 1, kh = f & 1;
        int o  = nb * BN + rb * 32 + (l & 31);
        int k0 = kt * BK + kh * 16 + (l >> 5) * 8;
        const fvec4* sw = (const fvec4*)(W + (size_t)o * KF + k0);
        const fvec4* sa = (const fvec4*)(A + (size_t)(o & 1023) * 1024 + (k0 & 1023));
        fvec4 w0 = sw[0], w1 = sw[1];
        fvec4 a0 = sa[0], a1 = sa[1];
        union { bf16x8 v; __hip_bfloat16 h[8]; } ov;
        ov.h[0] = __float2bfloat16(w0[0] + a0[0]); ov.h[1] = __float2bfloat16(w0[1] + a0[1]);
        ov.h[2] = __float2bfloat16(w0[2] + a0[2]); ov.h[3] = __float2bfloat16(w0[3] + a0[3]);
        ov.h[4] = __float2bfloat16(w1[0] + a1[0]); ov.h[5] = __float2bfloat16(w1[1] + a1[1]);
        ov.h[6] = __float2bfloat16(w1[2] + a1[2]); ov.h[7] = __float2bfloat16(w1[3] + a1[3]);
        *(bf16x8*)(dst + e) = ov.v;
    }
}

// ---------------- async global->LDS (width 16) ----------------
__device__ inline void gload_lds16(const __hip_bfloat16* g, __hip_bfloat16* l) {
    __builtin_amdgcn_global_load_lds(
        (const __attribute__((address_space(1))) unsigned int*)g,
        (__attribute__((address_space(3))) unsigned int*)l, 16, 0, 0);
}

// stage one K-tile (A panel + B panel) = 4 x global_load_lds_dwordx4
#define STG(tt, sl) { const __hip_bfloat16* ga = aP + (size_t)(tt) * TILE;       \
    gload_lds16(ga, As + (sl) * TILE + t8);                                      \
    gload_lds16(ga + 4096, As + (sl) * TILE + 4096 + t8);                        \
    const __hip_bfloat16* gb = bP + (size_t)(tt) * TILE;                         \
    gload_lds16(gb, Bs + (sl) * TILE + t8);                                      \
    gload_lds16(gb + 4096, Bs + (sl) * TILE + 4096 + t8); }

// one K-tile step: stage next tile into the other slot, 12 ds_read_b128 of
// this slot (fragment-major: base + lane*16B, conflict-free), 16 MFMA under
// setprio, vmcnt(0) (next tile's DMA had a full tile in flight), barrier.
#define STEP(SL, STAGE_STMT) {                                                   \
    STAGE_STMT;                                                                  \
    bf16x8 af[8], bfv[4];                                                        \
    {                                                                            \
        const __hip_bfloat16* ab = As + (SL) * TILE + aOff;                      \
        af[0] = *(const bf16x8*)(ab);                                            \
        af[1] = *(const bf16x8*)(ab + 512);                                      \
        af[2] = *(const bf16x8*)(ab + 1024);                                     \
        af[3] = *(const bf16x8*)(ab + 1536);                                     \
        af[4] = *(const bf16x8*)(ab + 2048);                                     \
        af[5] = *(const bf16x8*)(ab + 2560);                                     \
        af[6] = *(const bf16x8*)(ab + 3072);                                     \
        af[7] = *(const bf16x8*)(ab + 3584);                                     \
        const __hip_bfloat16* bb = Bs + (SL) * TILE + bOff;                      \
        bfv[0] = *(const bf16x8*)(bb);                                           \
        bfv[1] = *(const bf16x8*)(bb + 512);                                     \
        bfv[2] = *(const bf16x8*)(bb + 1024);                                    \
        bfv[3] = *(const bf16x8*)(bb + 1536);                                    \
    }                                                                            \
    __builtin_amdgcn_s_setprio(1);                                               \
    _Pragma("unroll") for (int fm = 0; fm < 4; ++fm)                             \
        _Pragma("unroll") for (int fn = 0; fn < 2; ++fn) {                       \
            acc[fm][fn] = __builtin_amdgcn_mfma_f32_32x32x16_bf16(               \
                af[fm * 2 + 0], bfv[fn * 2 + 0], acc[fm][fn], 0, 0, 0);          \
            acc[fm][fn] = __builtin_amdgcn_mfma_f32_32x32x16_bf16(               \
                af[fm * 2 + 1], bfv[fn * 2 + 1], acc[fm][fn], 0, 0, 0);          \
        }                                                                        \
    __builtin_amdgcn_s_setprio(0);                                               \
    asm volatile("s_waitcnt vmcnt(0)" ::: "memory");                             \
    __builtin_amdgcn_s_barrier();                                                \
    asm volatile("" ::: "memory"); }

__global__ __launch_bounds__(512, 4) void gemm_bf16_kernel(
    const __hip_bfloat16* __restrict__ xt, const __hip_bfloat16* __restrict__ wt,
    const float* __restrict__ bias, float* __restrict__ out) {
    extern __shared__ __hip_bfloat16 lds[];
    __hip_bfloat16* As = lds;                 // 2 slots * 8192 elems (32 KB)
    __hip_bfloat16* Bs = lds + 2 * TILE;      // 2 slots * 8192 elems (32 KB)

    // XCD chunking, nb-major inside chunk (B-panels L2-resident per XCD)
    int bid = blockIdx.x;                     // nwg = 1024
    int wg = (bid & 7) * 128 + (bid >> 3);
    int nb = wg >> 6;                         // 16 col-blocks
    int mb = wg & 63;                         // 64 row-blocks

    int tid = threadIdx.x;
    int lane = tid & 63;
    int wv = tid >> 6;                        // 8 waves
    int wm = wv >> 2, wn = wv & 3;            // 2 x 4 wave grid, 128x64 C each
    int t8 = tid * 8;

    // A frag (fm, kh): off = wm*4096 + fm*1024 + kh*512 + lane*8
    // B frag (fn, kh): off = wn*2048 + fn*1024 + kh*512 + lane*8
    int aOff = wm * 4096 + lane * 8;
    int bOff = wn * 2048 + lane * 8;

    const __hip_bfloat16* aP = xt + (size_t)mb * (KT * TILE) + t8;
    const __hip_bfloat16* bP = wt + (size_t)nb * (KT * TILE) + t8;

    f32x16 acc[4][2];
#pragma unroll
    for (int fm = 0; fm < 4; ++fm)
#pragma unroll
        for (int fn = 0; fn < 2; ++fn)
#pragma unroll
            for (int r = 0; r < 16; ++r) acc[fm][fn][r] = 0.f;

    // prologue: tile 0 -> slot 0; drain; barrier
    STG(0, 0);
    asm volatile("s_waitcnt vmcnt(0)" ::: "memory");
    __builtin_amdgcn_s_barrier();
    asm volatile("" ::: "memory");

    // main loop: tile t in slot t&1, stages tile t+1 into the other slot.
    // vmcnt(0)+barrier at step end makes tile t+1 resident for next step.
    for (int t = 0; t < KT; t += 2) {
        int n2 = t + 2; if (n2 >= KT) n2 = 0;    // tail: clamp (data unused)
        STEP(0, STG(t + 1, 1));
        STEP(1, STG(n2, 0));
    }
    // all DMA drained by the last STEP's vmcnt(0); nothing in flight here.

    // epilogue: 32x32 C/D layout: col = lane&31, row = (reg&3)+8*(reg>>2)+4*(lane>>5)
    int row0 = mb * BM + wm * 128;
    int col0 = nb * BN + wn * 64;
    int ln31 = lane & 31;
    int l5 = lane >> 5;
#pragma unroll
    for (int fn = 0; fn < 2; ++fn) {
        int col = col0 + fn * 32 + ln31;
        float bv = bias[col];
#pragma unroll
        for (int fm = 0; fm < 4; ++fm) {
            int rbase = row0 + fm * 32 + 4 * l5;
#pragma unroll
            for (int r = 0; r < 16; ++r) {
                int row = rbase + (r & 3) + 8 * (r >> 2);
                out[(size_t)row * NF + col] = acc[fm][fn][r] + bv;
            }
        }
    }
}

extern "C" void kernel_launch(void* const* d_in, const int* in_sizes, int n_in,
                              void* d_out, int out_size, void* d_ws, size_t ws_size,
                              hipStream_t stream) {
    const float* x = (const float*)d_in[0];
    const float* W = (const float*)d_in[1];
    const float* b = (const float*)d_in[2];
    const float* A = (const float*)d_in[3];
    float* out = (float*)d_out;

    size_t xt_elems = (size_t)MB * KT * TILE;       // 67.1M elems
    size_t wt_elems = (size_t)NB * KT * TILE;       // 16.8M elems
    size_t need = (xt_elems + wt_elems) * sizeof(__hip_bfloat16);
    if (ws_size < need) return;

    __hip_bfloat16* xt = (__hip_bfloat16*)d_ws;
    __hip_bfloat16* wt = xt + xt_elems;

    (void)hipFuncSetAttribute((const void*)gemm_bf16_kernel,
                              hipFuncAttributeMaxDynamicSharedMemorySize, 65536);

    tile_x_kernel<<<MB * KT, 256, 0, stream>>>(x, xt);
    tile_w_kernel<<<NB * KT, 256, 0, stream>>>(W, A, wt);
    gemm_bf16_kernel<<<MB * NB, 512, 65536, stream>>>(xt, wt, b, out);
}

// Round 11
// 641.910 us; speedup vs baseline: 16.7260x; 16.7260x over previous
//
#include <hip/hip_runtime.h>
#include <hip/hip_bf16.h>
#include <cstdint>

// MoRALinear: out[m,o] = sum_i x[m,i] * (W[o,i] + A[o&1023, i&1023]) + b[o]
// R11: 128x256 tile, BK=32, 8-wave (2Mx4N, per-wave C 64x64), mfma_32x32x16,
//      fragment-major panels, 3-slot LDS ring (72 KB) + launch_bounds(512,2)
//      -> 2 blocks/CU co-resident (VGPR ~110 <= 128 cap). Cross-block TLP
//      overlaps one block's MFMA epoch with the other's LDS epoch (m114).
//      NOTE: launch_bounds 2nd arg is min BLOCKS/CU (R10 evidence: (512,4)
//      gave VGPR cap 64 = 8 waves/SIMD).

typedef __attribute__((ext_vector_type(8))) short bf16x8;
typedef __attribute__((ext_vector_type(16))) float f32x16;
typedef __attribute__((ext_vector_type(4))) float fvec4;

static constexpr int MTOT = 16384;   // B*S
static constexpr int KF   = 4096;    // IN_F
static constexpr int NF   = 4096;    // OUT_F
static constexpr int BM = 128, BN = 256, BK = 32;
static constexpr int ATILE = BM * BK;         // 4096 elems (8 KB)
static constexpr int BTILE = BN * BK;         // 8192 elems (16 KB)
static constexpr int KT = KF / BK;            // 128 K-tiles
static constexpr int MB = MTOT / BM;          // 128
static constexpr int NB = NF / BN;            // 16

// ---------------- prep: x -> bf16, fragment-major 128-row panels -------------
// frag g = rb*2 + kh (rb 0..3): elem(g*512 + l*8 + j) =
//   x[mb*128 + rb*32 + (l&31)][kt*32 + kh*16 + (l>>5)*8 + j]
__global__ __launch_bounds__(256) void tile_x_kernel(const float* __restrict__ x,
                                                     __hip_bfloat16* __restrict__ xt) {
    int blk = blockIdx.x;               // mb*KT + kt ; grid = 128*128
    int mb = blk >> 7, kt = blk & 127;
    int tid = threadIdx.x;
    __hip_bfloat16* dst = xt + (size_t)blk * ATILE;
#pragma unroll
    for (int it = 0; it < 2; ++it) {
        int e = (it * 256 + tid) * 8;   // 0..4095
        int g = e >> 9;                 // frag 0..7
        int l = (e >> 3) & 63;          // lane 0..63
        int rb = g >> 1, kh = g & 1;
        int row = mb * BM + rb * 32 + (l & 31);
        int k0  = kt * BK + kh * 16 + (l >> 5) * 8;
        const fvec4* s = (const fvec4*)(x + (size_t)row * KF + k0);
        fvec4 v0 = s[0], v1 = s[1];
        union { bf16x8 v; __hip_bfloat16 h[8]; } o;
        o.h[0] = __float2bfloat16(v0[0]); o.h[1] = __float2bfloat16(v0[1]);
        o.h[2] = __float2bfloat16(v0[2]); o.h[3] = __float2bfloat16(v0[3]);
        o.h[4] = __float2bfloat16(v1[0]); o.h[5] = __float2bfloat16(v1[1]);
        o.h[6] = __float2bfloat16(v1[2]); o.h[7] = __float2bfloat16(v1[3]);
        *(bf16x8*)(dst + e) = o.v;
    }
}

// ---------------- prep: W' = W + tiled(A) -> bf16 fragment-major (unchanged) -
__global__ __launch_bounds__(256) void tile_w_kernel(const float* __restrict__ W,
                                                     const float* __restrict__ A,
                                                     __hip_bfloat16* __restrict__ wt) {
    int blk = blockIdx.x;               // nb*KT + kt ; grid = 16*128
    int nb = blk >> 7, kt = blk & 127;
    int tid = threadIdx.x;
    __hip_bfloat16* dst = wt + (size_t)blk * BTILE;
#pragma unroll
    for (int it = 0; it < 4; ++it) {
        int e = (it * 256 + tid) * 8;
        int f = e >> 9;
        int l = (e >> 3) & 63;
        int rb = f >> 1, kh = f & 1;
        int o  = nb * BN + rb * 32 + (l & 31);
        int k0 = kt * BK + kh * 16 + (l >> 5) * 8;
        const fvec4* sw = (const fvec4*)(W + (size_t)o * KF + k0);
        const fvec4* sa = (const fvec4*)(A + (size_t)(o & 1023) * 1024 + (k0 & 1023));
        fvec4 w0 = sw[0], w1 = sw[1];
        fvec4 a0 = sa[0], a1 = sa[1];
        union { bf16x8 v; __hip_bfloat16 h[8]; } ov;
        ov.h[0] = __float2bfloat16(w0[0] + a0[0]); ov.h[1] = __float2bfloat16(w0[1] + a0[1]);
        ov.h[2] = __float2bfloat16(w0[2] + a0[2]); ov.h[3] = __float2bfloat16(w0[3] + a0[3]);
        ov.h[4] = __float2bfloat16(w1[0] + a1[0]); ov.h[5] = __float2bfloat16(w1[1] + a1[1]);
        ov.h[6] = __float2bfloat16(w1[2] + a1[2]); ov.h[7] = __float2bfloat16(w1[3] + a1[3]);
        *(bf16x8*)(dst + e) = ov.v;
    }
}

// ---------------- async global->LDS (width 16) ----------------
__device__ inline void gload_lds16(const __hip_bfloat16* g, __hip_bfloat16* l) {
    __builtin_amdgcn_global_load_lds(
        (const __attribute__((address_space(1))) unsigned int*)g,
        (__attribute__((address_space(3))) unsigned int*)l, 16, 0, 0);
}

// stage one K-tile: A = 1 gload (4096 elems / 512 thr), B = 2 gloads
#define STG(tt, sl) {                                                            \
    int tc_ = (tt) < KT ? (tt) : 0;  /* tail clamp: data unused */               \
    gload_lds16(aP + (size_t)tc_ * ATILE + t8, As + (sl) * ATILE + t8);          \
    const __hip_bfloat16* gb_ = bP + (size_t)tc_ * BTILE + t8;                   \
    gload_lds16(gb_, Bs + (sl) * BTILE + t8);                                    \
    gload_lds16(gb_ + 4096, Bs + (sl) * BTILE + 4096 + t8); }

// one K-tile step (slot SL): stage tile t+2, 8 ds_read_b128 (frag-major:
// base + lane*16B, conflict-free), 8 MFMA under setprio, vmcnt(3) (drains
// tile t+1's 3 loads, leaves t+2's 3 in flight), barrier.
#define STEP(SL, STAGE_STMT) {                                                   \
    STAGE_STMT;                                                                  \
    bf16x8 af[4], bfv[4];                                                        \
    {                                                                            \
        const __hip_bfloat16* ab = As + (SL) * ATILE + aOff;                     \
        af[0] = *(const bf16x8*)(ab);                                            \
        af[1] = *(const bf16x8*)(ab + 512);                                      \
        af[2] = *(const bf16x8*)(ab + 1024);                                     \
        af[3] = *(const bf16x8*)(ab + 1536);                                     \
        const __hip_bfloat16* bb = Bs + (SL) * BTILE + bOff;                     \
        bfv[0] = *(const bf16x8*)(bb);                                           \
        bfv[1] = *(const bf16x8*)(bb + 512);                                     \
        bfv[2] = *(const bf16x8*)(bb + 1024);                                    \
        bfv[3] = *(const bf16x8*)(bb + 1536);                                    \
    }                                                                            \
    __builtin_amdgcn_s_setprio(1);                                               \
    acc[0][0] = __builtin_amdgcn_mfma_f32_32x32x16_bf16(af[0], bfv[0], acc[0][0], 0, 0, 0); \
    acc[0][1] = __builtin_amdgcn_mfma_f32_32x32x16_bf16(af[0], bfv[2], acc[0][1], 0, 0, 0); \
    acc[1][0] = __builtin_amdgcn_mfma_f32_32x32x16_bf16(af[2], bfv[0], acc[1][0], 0, 0, 0); \
    acc[1][1] = __builtin_amdgcn_mfma_f32_32x32x16_bf16(af[2], bfv[2], acc[1][1], 0, 0, 0); \
    acc[0][0] = __builtin_amdgcn_mfma_f32_32x32x16_bf16(af[1], bfv[1], acc[0][0], 0, 0, 0); \
    acc[0][1] = __builtin_amdgcn_mfma_f32_32x32x16_bf16(af[1], bfv[3], acc[0][1], 0, 0, 0); \
    acc[1][0] = __builtin_amdgcn_mfma_f32_32x32x16_bf16(af[3], bfv[1], acc[1][0], 0, 0, 0); \
    acc[1][1] = __builtin_amdgcn_mfma_f32_32x32x16_bf16(af[3], bfv[3], acc[1][1], 0, 0, 0); \
    __builtin_amdgcn_s_setprio(0);                                               \
    asm volatile("s_waitcnt vmcnt(3)" ::: "memory");                             \
    __builtin_amdgcn_s_barrier();                                                \
    asm volatile("" ::: "memory"); }

__global__ __launch_bounds__(512, 2) void gemm_bf16_kernel(
    const __hip_bfloat16* __restrict__ xt, const __hip_bfloat16* __restrict__ wt,
    const float* __restrict__ bias, float* __restrict__ out) {
    extern __shared__ __hip_bfloat16 lds[];
    __hip_bfloat16* As = lds;                 // 3 slots * 4096 elems (24 KB)
    __hip_bfloat16* Bs = lds + 3 * ATILE;     // 3 slots * 8192 elems (48 KB)

    // XCD chunking, nb-major inside chunk (B-panels L2-resident; A re-reads
    // hit L3: 128 MB < 256 MB)
    int bid = blockIdx.x;                     // nwg = 2048
    int wg = (bid & 7) * 256 + (bid >> 3);
    int nb = wg >> 7;                         // 16 col-blocks
    int mb = wg & 127;                        // 128 row-blocks

    int tid = threadIdx.x;
    int lane = tid & 63;
    int wv = tid >> 6;                        // 8 waves
    int wm = wv >> 2, wn = wv & 3;            // 2 x 4 wave grid, 64x64 C each
    int t8 = tid * 8;

    // A frag (fm, kh): off = wm*2048 + fm*1024 + kh*512 + lane*8
    // B frag (fn, kh): off = wn*2048 + fn*1024 + kh*512 + lane*8
    int aOff = wm * 2048 + lane * 8;
    int bOff = wn * 2048 + lane * 8;

    const __hip_bfloat16* aP = xt + (size_t)mb * (KT * ATILE);
    const __hip_bfloat16* bP = wt + (size_t)nb * (KT * BTILE);

    f32x16 acc[2][2];
#pragma unroll
    for (int fm = 0; fm < 2; ++fm)
#pragma unroll
        for (int fn = 0; fn < 2; ++fn)
#pragma unroll
            for (int r = 0; r < 16; ++r) acc[fm][fn][r] = 0.f;

    // prologue: tiles 0,1 -> slots 0,1 (6 loads); vmcnt(3) drains tile 0
    STG(0, 0); STG(1, 1);
    asm volatile("s_waitcnt vmcnt(3)" ::: "memory");
    __builtin_amdgcn_s_barrier();
    asm volatile("" ::: "memory");

    // main loop: tile t in slot t%3, stages tile t+2 into slot (t+2)%3.
    // 42 x 3 = 126 tiles, then 2 tail steps (126: slot 0, 127: slot 1).
    for (int j = 0; j < 42; ++j) {
        int t0 = 3 * j;
        STEP(0, STG(t0 + 2, 2));
        STEP(1, STG(t0 + 3, 0));
        STEP(2, STG(t0 + 4, 1));
    }
    STEP(0, STG(128, 2));    // t=126 (stage clamps; data unused)
    STEP(1, STG(129, 0));    // t=127
    // drain all LDS-DMA before kernel end
    asm volatile("s_waitcnt vmcnt(0)" ::: "memory");

    // epilogue: 32x32 C/D: col = lane&31, row = (reg&3)+8*(reg>>2)+4*(lane>>5)
    int row0 = mb * BM + wm * 64;
    int col0 = nb * BN + wn * 64;
    int ln31 = lane & 31;
    int l5 = lane >> 5;
#pragma unroll
    for (int fn = 0; fn < 2; ++fn) {
        int col = col0 + fn * 32 + ln31;
        float bv = bias[col];
#pragma unroll
        for (int fm = 0; fm < 2; ++fm) {
            int rbase = row0 + fm * 32 + 4 * l5;
#pragma unroll
            for (int r = 0; r < 16; ++r) {
                int row = rbase + (r & 3) + 8 * (r >> 2);
                out[(size_t)row * NF + col] = acc[fm][fn][r] + bv;
            }
        }
    }
}

extern "C" void kernel_launch(void* const* d_in, const int* in_sizes, int n_in,
                              void* d_out, int out_size, void* d_ws, size_t ws_size,
                              hipStream_t stream) {
    const float* x = (const float*)d_in[0];
    const float* W = (const float*)d_in[1];
    const float* b = (const float*)d_in[2];
    const float* A = (const float*)d_in[3];
    float* out = (float*)d_out;

    size_t xt_elems = (size_t)MB * KT * ATILE;      // 67.1M elems
    size_t wt_elems = (size_t)NB * KT * BTILE;      // 16.8M elems
    size_t need = (xt_elems + wt_elems) * sizeof(__hip_bfloat16);
    if (ws_size < need) return;

    __hip_bfloat16* xt = (__hip_bfloat16*)d_ws;
    __hip_bfloat16* wt = xt + xt_elems;

    (void)hipFuncSetAttribute((const void*)gemm_bf16_kernel,
                              hipFuncAttributeMaxDynamicSharedMemorySize, 73728);

    tile_x_kernel<<<MB * KT, 256, 0, stream>>>(x, xt);
    tile_w_kernel<<<NB * KT, 256, 0, stream>>>(W, A, wt);
    gemm_bf16_kernel<<<MB * NB, 512, 73728, stream>>>(xt, wt, b, out);
}

// Round 12
// 640.675 us; speedup vs baseline: 16.7582x; 1.0019x over previous
//
#include <hip/hip_runtime.h>
#include <hip/hip_bf16.h>
#include <cstdint>

// MoRALinear: out[m,o] = sum_i x[m,i] * (W[o,i] + A[o&1023, i&1023]) + b[o]
// R11: 128x256 tile, BK=32, 8-wave (2Mx4N, per-wave C 64x64), mfma_32x32x16,
//      fragment-major panels, 3-slot LDS ring (72 KB) + launch_bounds(512,2)
//      -> 2 blocks/CU co-resident (VGPR ~110 <= 128 cap). Cross-block TLP
//      overlaps one block's MFMA epoch with the other's LDS epoch (m114).
//      NOTE: launch_bounds 2nd arg is min BLOCKS/CU (R10 evidence: (512,4)
//      gave VGPR cap 64 = 8 waves/SIMD).

typedef __attribute__((ext_vector_type(8))) short bf16x8;
typedef __attribute__((ext_vector_type(16))) float f32x16;
typedef __attribute__((ext_vector_type(4))) float fvec4;

static constexpr int MTOT = 16384;   // B*S
static constexpr int KF   = 4096;    // IN_F
static constexpr int NF   = 4096;    // OUT_F
static constexpr int BM = 128, BN = 256, BK = 32;
static constexpr int ATILE = BM * BK;         // 4096 elems (8 KB)
static constexpr int BTILE = BN * BK;         // 8192 elems (16 KB)
static constexpr int KT = KF / BK;            // 128 K-tiles
static constexpr int MB = MTOT / BM;          // 128
static constexpr int NB = NF / BN;            // 16

// ---------------- prep: x -> bf16, fragment-major 128-row panels -------------
// frag g = rb*2 + kh (rb 0..3): elem(g*512 + l*8 + j) =
//   x[mb*128 + rb*32 + (l&31)][kt*32 + kh*16 + (l>>5)*8 + j]
__global__ __launch_bounds__(256) void tile_x_kernel(const float* __restrict__ x,
                                                     __hip_bfloat16* __restrict__ xt) {
    int blk = blockIdx.x;               // mb*KT + kt ; grid = 128*128
    int mb = blk >> 7, kt = blk & 127;
    int tid = threadIdx.x;
    __hip_bfloat16* dst = xt + (size_t)blk * ATILE;
#pragma unroll
    for (int it = 0; it < 2; ++it) {
        int e = (it * 256 + tid) * 8;   // 0..4095
        int g = e >> 9;                 // frag 0..7
        int l = (e >> 3) & 63;          // lane 0..63
        int rb = g >> 1, kh = g & 1;
        int row = mb * BM + rb * 32 + (l & 31);
        int k0  = kt * BK + kh * 16 + (l >> 5) * 8;
        const fvec4* s = (const fvec4*)(x + (size_t)row * KF + k0);
        fvec4 v0 = s[0], v1 = s[1];
        union { bf16x8 v; __hip_bfloat16 h[8]; } o;
        o.h[0] = __float2bfloat16(v0[0]); o.h[1] = __float2bfloat16(v0[1]);
        o.h[2] = __float2bfloat16(v0[2]); o.h[3] = __float2bfloat16(v0[3]);
        o.h[4] = __float2bfloat16(v1[0]); o.h[5] = __float2bfloat16(v1[1]);
        o.h[6] = __float2bfloat16(v1[2]); o.h[7] = __float2bfloat16(v1[3]);
        *(bf16x8*)(dst + e) = o.v;
    }
}

// ---------------- prep: W' = W + tiled(A) -> bf16 fragment-major (unchanged) -
__global__ __launch_bounds__(256) void tile_w_kernel(const float* __restrict__ W,
                                                     const float* __restrict__ A,
                                                     __hip_bfloat16* __restrict__ wt) {
    int blk = blockIdx.x;               // nb*KT + kt ; grid = 16*128
    int nb = blk >> 7, kt = blk & 127;
    int tid = threadIdx.x;
    __hip_bfloat16* dst = wt + (size_t)blk * BTILE;
#pragma unroll
    for (int it = 0; it < 4; ++it) {
        int e = (it * 256 + tid) * 8;
        int f = e >> 9;
        int l = (e >> 3) & 63;
        int rb = f >> 1, kh = f & 1;
        int o  = nb * BN + rb * 32 + (l & 31);
        int k0 = kt * BK + kh * 16 + (l >> 5) * 8;
        const fvec4* sw = (const fvec4*)(W + (size_t)o * KF + k0);
        const fvec4* sa = (const fvec4*)(A + (size_t)(o & 1023) * 1024 + (k0 & 1023));
        fvec4 w0 = sw[0], w1 = sw[1];
        fvec4 a0 = sa[0], a1 = sa[1];
        union { bf16x8 v; __hip_bfloat16 h[8]; } ov;
        ov.h[0] = __float2bfloat16(w0[0] + a0[0]); ov.h[1] = __float2bfloat16(w0[1] + a0[1]);
        ov.h[2] = __float2bfloat16(w0[2] + a0[2]); ov.h[3] = __float2bfloat16(w0[3] + a0[3]);
        ov.h[4] = __float2bfloat16(w1[0] + a1[0]); ov.h[5] = __float2bfloat16(w1[1] + a1[1]);
        ov.h[6] = __float2bfloat16(w1[2] + a1[2]); ov.h[7] = __float2bfloat16(w1[3] + a1[3]);
        *(bf16x8*)(dst + e) = ov.v;
    }
}

// ---------------- async global->LDS (width 16) ----------------
__device__ inline void gload_lds16(const __hip_bfloat16* g, __hip_bfloat16* l) {
    __builtin_amdgcn_global_load_lds(
        (const __attribute__((address_space(1))) unsigned int*)g,
        (__attribute__((address_space(3))) unsigned int*)l, 16, 0, 0);
}

// stage one K-tile: A = 1 gload (4096 elems / 512 thr), B = 2 gloads
#define STG(tt, sl) {                                                            \
    int tc_ = (tt) < KT ? (tt) : 0;  /* tail clamp: data unused */               \
    gload_lds16(aP + (size_t)tc_ * ATILE + t8, As + (sl) * ATILE + t8);          \
    const __hip_bfloat16* gb_ = bP + (size_t)tc_ * BTILE + t8;                   \
    gload_lds16(gb_, Bs + (sl) * BTILE + t8);                                    \
    gload_lds16(gb_ + 4096, Bs + (sl) * BTILE + 4096 + t8); }

// one K-tile step (slot SL): stage tile t+2, 8 ds_read_b128 (frag-major:
// base + lane*16B, conflict-free), 8 MFMA under setprio, vmcnt(3) (drains
// tile t+1's 3 loads, leaves t+2's 3 in flight), barrier.
#define STEP(SL, STAGE_STMT) {                                                   \
    STAGE_STMT;                                                                  \
    bf16x8 af[4], bfv[4];                                                        \
    {                                                                            \
        const __hip_bfloat16* ab = As + (SL) * ATILE + aOff;                     \
        af[0] = *(const bf16x8*)(ab);                                            \
        af[1] = *(const bf16x8*)(ab + 512);                                      \
        af[2] = *(const bf16x8*)(ab + 1024);                                     \
        af[3] = *(const bf16x8*)(ab + 1536);                                     \
        const __hip_bfloat16* bb = Bs + (SL) * BTILE + bOff;                     \
        bfv[0] = *(const bf16x8*)(bb);                                           \
        bfv[1] = *(const bf16x8*)(bb + 512);                                     \
        bfv[2] = *(const bf16x8*)(bb + 1024);                                    \
        bfv[3] = *(const bf16x8*)(bb + 1536);                                    \
    }                                                                            \
    __builtin_amdgcn_s_setprio(1);                                               \
    acc[0][0] = __builtin_amdgcn_mfma_f32_32x32x16_bf16(af[0], bfv[0], acc[0][0], 0, 0, 0); \
    acc[0][1] = __builtin_amdgcn_mfma_f32_32x32x16_bf16(af[0], bfv[2], acc[0][1], 0, 0, 0); \
    acc[1][0] = __builtin_amdgcn_mfma_f32_32x32x16_bf16(af[2], bfv[0], acc[1][0], 0, 0, 0); \
    acc[1][1] = __builtin_amdgcn_mfma_f32_32x32x16_bf16(af[2], bfv[2], acc[1][1], 0, 0, 0); \
    acc[0][0] = __builtin_amdgcn_mfma_f32_32x32x16_bf16(af[1], bfv[1], acc[0][0], 0, 0, 0); \
    acc[0][1] = __builtin_amdgcn_mfma_f32_32x32x16_bf16(af[1], bfv[3], acc[0][1], 0, 0, 0); \
    acc[1][0] = __builtin_amdgcn_mfma_f32_32x32x16_bf16(af[3], bfv[1], acc[1][0], 0, 0, 0); \
    acc[1][1] = __builtin_amdgcn_mfma_f32_32x32x16_bf16(af[3], bfv[3], acc[1][1], 0, 0, 0); \
    __builtin_amdgcn_s_setprio(0);                                               \
    asm volatile("s_waitcnt vmcnt(3)" ::: "memory");                             \
    __builtin_amdgcn_s_barrier();                                                \
    asm volatile("" ::: "memory"); }

__global__ __launch_bounds__(512, 2) void gemm_bf16_kernel(
    const __hip_bfloat16* __restrict__ xt, const __hip_bfloat16* __restrict__ wt,
    const float* __restrict__ bias, float* __restrict__ out) {
    extern __shared__ __hip_bfloat16 lds[];
    __hip_bfloat16* As = lds;                 // 3 slots * 4096 elems (24 KB)
    __hip_bfloat16* Bs = lds + 3 * ATILE;     // 3 slots * 8192 elems (48 KB)

    // XCD chunking, nb-major inside chunk (B-panels L2-resident; A re-reads
    // hit L3: 128 MB < 256 MB)
    int bid = blockIdx.x;                     // nwg = 2048
    int wg = (bid & 7) * 256 + (bid >> 3);
    int nb = wg >> 7;                         // 16 col-blocks
    int mb = wg & 127;                        // 128 row-blocks

    int tid = threadIdx.x;
    int lane = tid & 63;
    int wv = tid >> 6;                        // 8 waves
    int wm = wv >> 2, wn = wv & 3;            // 2 x 4 wave grid, 64x64 C each
    int t8 = tid * 8;

    // A frag (fm, kh): off = wm*2048 + fm*1024 + kh*512 + lane*8
    // B frag (fn, kh): off = wn*2048 + fn*1024 + kh*512 + lane*8
    int aOff = wm * 2048 + lane * 8;
    int bOff = wn * 2048 + lane * 8;

    const __hip_bfloat16* aP = xt + (size_t)mb * (KT * ATILE);
    const __hip_bfloat16* bP = wt + (size_t)nb * (KT * BTILE);

    f32x16 acc[2][2];
#pragma unroll
    for (int fm = 0; fm < 2; ++fm)
#pragma unroll
        for (int fn = 0; fn < 2; ++fn)
#pragma unroll
            for (int r = 0; r < 16; ++r) acc[fm][fn][r] = 0.f;

    // prologue: tiles 0,1 -> slots 0,1 (6 loads); vmcnt(3) drains tile 0
    STG(0, 0); STG(1, 1);
    asm volatile("s_waitcnt vmcnt(3)" ::: "memory");
    __builtin_amdgcn_s_barrier();
    asm volatile("" ::: "memory");

    // main loop: tile t in slot t%3, stages tile t+2 into slot (t+2)%3.
    // 42 x 3 = 126 tiles, then 2 tail steps (126: slot 0, 127: slot 1).
    for (int j = 0; j < 42; ++j) {
        int t0 = 3 * j;
        STEP(0, STG(t0 + 2, 2));
        STEP(1, STG(t0 + 3, 0));
        STEP(2, STG(t0 + 4, 1));
    }
    STEP(0, STG(128, 2));    // t=126 (stage clamps; data unused)
    STEP(1, STG(129, 0));    // t=127
    // drain all LDS-DMA before kernel end
    asm volatile("s_waitcnt vmcnt(0)" ::: "memory");

    // epilogue: 32x32 C/D: col = lane&31, row = (reg&3)+8*(reg>>2)+4*(lane>>5)
    int row0 = mb * BM + wm * 64;
    int col0 = nb * BN + wn * 64;
    int ln31 = lane & 31;
    int l5 = lane >> 5;
#pragma unroll
    for (int fn = 0; fn < 2; ++fn) {
        int col = col0 + fn * 32 + ln31;
        float bv = bias[col];
#pragma unroll
        for (int fm = 0; fm < 2; ++fm) {
            int rbase = row0 + fm * 32 + 4 * l5;
#pragma unroll
            for (int r = 0; r < 16; ++r) {
                int row = rbase + (r & 3) + 8 * (r >> 2);
                out[(size_t)row * NF + col] = acc[fm][fn][r] + bv;
            }
        }
    }
}

extern "C" void kernel_launch(void* const* d_in, const int* in_sizes, int n_in,
                              void* d_out, int out_size, void* d_ws, size_t ws_size,
                              hipStream_t stream) {
    const float* x = (const float*)d_in[0];
    const float* W = (const float*)d_in[1];
    const float* b = (const float*)d_in[2];
    const float* A = (const float*)d_in[3];
    float* out = (float*)d_out;

    size_t xt_elems = (size_t)MB * KT * ATILE;      // 67.1M elems
    size_t wt_elems = (size_t)NB * KT * BTILE;      // 16.8M elems
    size_t need = (xt_elems + wt_elems) * sizeof(__hip_bfloat16);
    if (ws_size < need) return;

    __hip_bfloat16* xt = (__hip_bfloat16*)d_ws;
    __hip_bfloat16* wt = xt + xt_elems;

    (void)hipFuncSetAttribute((const void*)gemm_bf16_kernel,
                              hipFuncAttributeMaxDynamicSharedMemorySize, 73728);

    tile_x_kernel<<<MB * KT, 256, 0, stream>>>(x, xt);
    tile_w_kernel<<<NB * KT, 256, 0, stream>>>(W, A, wt);
    gemm_bf16_kernel<<<MB * NB, 512, 73728, stream>>>(xt, wt, b, out);
}